// Round 7
// baseline (124.728 us; speedup 1.0000x reference)
//
#include <hip/hip_runtime.h>

namespace {

constexpr int T_STEPS = 1024;
constexpr int BATCH   = 16;
constexpr int NNEUR   = 2048;
constexpr int MCOLS   = 512;
constexpr int BN      = BATCH * NNEUR;   // 32768

constexpr double DT_D   = 1e-7;
constexpr double TAU_D  = 1e-4;

constexpr float DT_F     = 1e-7f;
constexpr float CMEM_F   = 1e-12f;
constexpr float GLEAK_F  = 1e-9f;
constexpr float VTH_F    = 0.7f;             // VTH * GAIN
constexpr float REFRAC_F = 1e-6f;
constexpr float AINC_F   = 5e-11f;
constexpr float DECAY_F  = (float)(1.0 - DT_D / TAU_D);   // 0.999f
constexpr float VRESET_F = 0.0f;

// Producer/consumer geometry: 256 blocks x 384 threads.
// waves 0-1: compute (128 neurons, 1/thread). waves 2-5: loaders.
constexpr int NPB     = 128;                  // neurons per block
constexpr int C_STEPS = 8;                    // timesteps per buffer
constexpr int NBUF    = T_STEPS / C_STEPS;    // 128
constexpr int RPW     = 6;                    // rows per loader wave per buffer
constexpr int AHEAD   = 4;                    // loader register ring depth
constexpr int SLOT_F  = 3 * C_STEPS * NPB;    // floats per LDS slot (3072)
constexpr size_t BUF_STRIDE = (size_t)C_STEPS * BN;   // floats between buffers

} // namespace

// One LIF step, byte-identical numerics to the passing kernels.
#define LIF_STEP(ec, ic, vc, tidx)                                         \
    do {                                                                   \
        float t      = (float)(tidx) * DT_F;                               \
        bool  active = (t - ls) >= REFRAC_F;                               \
        float totI   = ((ec) - A) + (ic);                                  \
        float Vn     = (V + (DT_F * (totI - GLEAK_F * V)) / CMEM_F) + (vc);\
        float An     = A * DECAY_F;                                        \
        float V1     = active ? Vn : V;                                    \
        float A1     = active ? A1n_unused : A;                            \
        (void)0;                                                           \
    } while (0)
#undef LIF_STEP
#define LIF_STEP(ec, ic, vc, tidx)                                         \
    do {                                                                   \
        float t      = (float)(tidx) * DT_F;                               \
        bool  active = (t - ls) >= REFRAC_F;                               \
        float totI   = ((ec) - A) + (ic);                                  \
        float Vn     = (V + (DT_F * (totI - GLEAK_F * V)) / CMEM_F) + (vc);\
        float An     = A * DECAY_F;                                        \
        float V1     = active ? Vn : V;                                    \
        float A1     = active ? An : A;                                    \
        bool  spike  = active && (V1 >= VTH_F);                            \
        V  = spike ? VRESET_F : V1;                                        \
        A  = spike ? (A1 + AINC_F) : A1;                                   \
        ls = spike ? t : ls;                                               \
        count += spike ? 1 : 0;                                            \
    } while (0)

__global__ __launch_bounds__(384, 1) void lif_sim_kernel(
    const float* __restrict__ ext,
    const float* __restrict__ inz,
    const float* __restrict__ vnz,
    float* __restrict__ rates)
{
    // 2-slot handoff buffer: [slot][array][t][neuron] = 2 x 12 KB
    __shared__ float slotmem[2][3][C_STEPS][NPB];

    const int tid  = threadIdx.x;
    const int lane = tid & 63;
    const int w    = tid >> 6;          // 0..5
    const int n0   = blockIdx.x * NPB;

    if (w >= 2) {
        // ---------------- loader waves (4) ----------------
        const int lw = w - 2;           // 0..3
        const float* pg[RPW];           // advancing global row pointers
        float*       pl[RPW];           // LDS slot-0 destinations
#pragma unroll
        for (int i = 0; i < RPW; ++i) {
            const int r  = lw * RPW + i;    // 0..23
            const int a  = r >> 3;          // array select
            const int tt = r & 7;           // timestep within buffer
            const float* ba = (a == 0) ? ext : ((a == 1) ? inz : vnz);
            pg[i] = ba + (size_t)tt * BN + (n0 + lane * 2);
            pl[i] = &slotmem[0][a][tt][lane * 2];
        }

        float2 rb0[RPW], rb1[RPW], rb2[RPW], rb3[RPW];

        // Inline-asm loads: asm volatile preserves program order among
        // themselves and vs the vmcnt waits, and forces the ring registers
        // to stay live — the compiler cannot collapse the pipeline depth
        // (R6 failure mode: VGPR_Count=40 proved the ring was dissolved).
#define LISSUE(RB)                                                         \
        do {                                                               \
            _Pragma("unroll")                                              \
            for (int i = 0; i < RPW; ++i) {                                \
                asm volatile("global_load_dwordx2 %0, %1, off"             \
                             : "=v"(RB[i]) : "v"(pg[i]) : "memory");       \
                pg[i] += BUF_STRIDE;                                       \
            }                                                              \
        } while (0)

        // prologue: buffers 0..3 in flight (24 dwordx2 per wave)
        LISSUE(rb0); LISSUE(rb1); LISSUE(rb2); LISSUE(rb3);

        // Per iteration J (LDS slot = J%2, reg-buf = J%4):
        //  vmcnt(W): buffer J's 6 loads landed (W = 6 * #future buffers)
        //  ds_write rows -> slot ; lgkmcnt(0) publishes (and frees regs)
        //  reissue J+4 into same regs ; raw barrier (never drains vmcnt)
#define LITER(RB, S, WLIT, DOISS)                                          \
        do {                                                               \
            asm volatile("s_waitcnt vmcnt(" #WLIT ")" ::: "memory");       \
            __builtin_amdgcn_sched_barrier(0);                             \
            _Pragma("unroll")                                              \
            for (int i = 0; i < RPW; ++i)                                  \
                *(float2*)(pl[i] + (S) * SLOT_F) = RB[i];                  \
            asm volatile("s_waitcnt lgkmcnt(0)" ::: "memory");             \
            __builtin_amdgcn_sched_barrier(0);                             \
            if (DOISS) { LISSUE(RB); }                                     \
            __builtin_amdgcn_sched_barrier(0);                             \
            __builtin_amdgcn_s_barrier();                                  \
            __builtin_amdgcn_sched_barrier(0);                             \
        } while (0)

        for (int jb = 0; jb < (NBUF / 4) - 1; ++jb) {
            LITER(rb0, 0, 18, 1);
            LITER(rb1, 1, 18, 1);
            LITER(rb2, 0, 18, 1);
            LITER(rb3, 1, 18, 1);
        }
        // epilogue: drain 24 -> 18 -> 12 -> 6 -> 0 outstanding
        LITER(rb0, 0, 18, 0);
        LITER(rb1, 1, 12, 0);
        LITER(rb2, 0, 6,  0);
        LITER(rb3, 1, 0,  0);

#undef LITER
#undef LISSUE
    } else {
        // ---------------- compute waves (2): 1 neuron per thread ----------------
        float V = 0.0f, A = 0.0f, ls = -1e9f;
        int count = 0;

        for (int jb = 0; jb < NBUF / 4; ++jb) {
#pragma unroll
            for (int u = 0; u < 4; ++u) {
                __builtin_amdgcn_s_barrier();
                __builtin_amdgcn_sched_barrier(0);
                const int s = u & 1;
#pragma unroll
                for (int c = 0; c < C_STEPS; ++c) {
                    float ec = slotmem[s][0][c][tid];
                    float ic = slotmem[s][1][c][tid];
                    float vc = slotmem[s][2][c][tid];
                    LIF_STEP(ec, ic, vc, (jb * 4 + u) * C_STEPS + c);
                }
                __builtin_amdgcn_sched_barrier(0);   // keep reads inside window
            }
        }
        rates[n0 + tid] = (float)count * (1.0f / 1024.0f);
    }
}

// ---------------- readout: rates[16,2048] @ (Gn*0.1)[2048,512] ----------------
constexpr int KC   = 8;
constexpr int KCH  = NNEUR / KC;    // 256 k per chunk
constexpr int KSUB = 4;             // waves per block splitting the chunk
constexpr int KPT  = KCH / KSUB;    // 64 k per thread

__global__ __launch_bounds__(256) void readout_partial_kernel(
    const float* __restrict__ rates,
    const float* __restrict__ G,
    const float* __restrict__ cn,
    float* __restrict__ part)
{
    __shared__ float red[KSUB][64][BATCH + 1];

    const int tid = threadIdx.x;
    const int ml  = tid & 63;
    const int s   = tid >> 6;
    const int m   = blockIdx.x * 64 + ml;
    const int kc  = blockIdx.y;
    const int k0  = kc * KCH + s * KPT;

    float acc[BATCH];
#pragma unroll
    for (int b = 0; b < BATCH; ++b) acc[b] = 0.0f;

#pragma unroll 4
    for (int k = k0; k < k0 + KPT; ++k) {
        float g = G[(size_t)k * MCOLS + m];
        float c = cn[(size_t)k * MCOLS + m];
        float w = fmaxf(1e-8f, g * (1.0f + 0.1118f * c)) * 0.1f;  // Gn * READ_V
#pragma unroll
        for (int b = 0; b < BATCH; ++b) {
            acc[b] = fmaf(rates[b * NNEUR + k], w, acc[b]);
        }
    }

#pragma unroll
    for (int b = 0; b < BATCH; ++b) red[s][ml][b] = acc[b];
    __syncthreads();

    if (s == 0) {
#pragma unroll
        for (int b = 0; b < BATCH; ++b) {
            float v = ((red[0][ml][b] + red[1][ml][b]) + red[2][ml][b]) + red[3][ml][b];
            part[((size_t)kc * BATCH + b) * MCOLS + m] = v;
        }
    }
}

__global__ __launch_bounds__(256) void readout_reduce_kernel(
    const float* __restrict__ part,
    float* __restrict__ out)
{
    const int i = blockIdx.x * 256 + threadIdx.x;  // 0..8191 = b*512+m
    float s = 0.0f;
#pragma unroll
    for (int kc = 0; kc < KC; ++kc) {
        s += part[kc * (BATCH * MCOLS) + i];
    }
    out[i] = s;
}

extern "C" void kernel_launch(void* const* d_in, const int* in_sizes, int n_in,
                              void* d_out, int out_size, void* d_ws, size_t ws_size,
                              hipStream_t stream)
{
    const float* ext = (const float*)d_in[0];   // [T,B,N]
    const float* inz = (const float*)d_in[1];   // [T,B,N]
    const float* vnz = (const float*)d_in[2];   // [T,B,N]
    const float* G   = (const float*)d_in[3];   // [N,M]
    const float* cn  = (const float*)d_in[4];   // [N,M]
    float* out = (float*)d_out;                 // [B,M] = 8192

    float* rates = (float*)d_ws;                // 32768 floats
    float* part  = rates + BN;                  // 8*16*512 = 65536 floats

    lif_sim_kernel<<<BN / NPB, 384, 0, stream>>>(ext, inz, vnz, rates);
    readout_partial_kernel<<<dim3(MCOLS / 64, KC), 256, 0, stream>>>(rates, G, cn, part);
    readout_reduce_kernel<<<(BATCH * MCOLS) / 256, 256, 0, stream>>>(part, out);
}

// Round 8
// 113.139 us; speedup vs baseline: 1.1024x; 1.1024x over previous
//
#include <hip/hip_runtime.h>

namespace {

constexpr int T_STEPS = 1024;
constexpr int BATCH   = 16;
constexpr int NNEUR   = 2048;
constexpr int MCOLS   = 512;
constexpr int BN      = BATCH * NNEUR;   // 32768

constexpr double DT_D   = 1e-7;
constexpr double TAU_D  = 1e-4;

constexpr float DT_F     = 1e-7f;
constexpr float CMEM_F   = 1e-12f;
constexpr float GLEAK_F  = 1e-9f;
constexpr float VTH_F    = 0.7f;             // VTH * GAIN
constexpr float REFRAC_F = 1e-6f;
constexpr float AINC_F   = 5e-11f;
constexpr float DECAY_F  = (float)(1.0 - DT_D / TAU_D);   // 0.999f
constexpr float VRESET_F = 0.0f;

// 256 blocks x 384 threads: waves 0-1 compute (128 neurons, 1/thread),
// waves 2-5 are loaders issuing width-4 global_load_lds (256B contiguous
// single-segment per instruction — LDS-direct, so no register ring for the
// compiler to dissolve; depth survives by construction, like R3).
constexpr int NPB     = 128;                  // neurons per block
constexpr int C_STEPS = 8;                    // timesteps per buffer
constexpr int NBUF    = T_STEPS / C_STEPS;    // 128
constexpr int RING    = 6;                    // LDS slots (6 x 12 KB = 72 KB)
constexpr int AHEAD   = 4;                    // buffers in flight
constexpr int IPW     = 12;                   // instrs per loader wave per buffer
constexpr size_t BUF_STRIDE = (size_t)C_STEPS * BN;   // floats between buffers

} // namespace

// One LIF step, byte-identical numerics to all passing rounds.
#define LIF_STEP(ec, ic, vc, tidx)                                         \
    do {                                                                   \
        float t      = (float)(tidx) * DT_F;                               \
        bool  active = (t - ls) >= REFRAC_F;                               \
        float totI   = ((ec) - A) + (ic);                                  \
        float Vn     = (V + (DT_F * (totI - GLEAK_F * V)) / CMEM_F) + (vc);\
        float An     = A * DECAY_F;                                        \
        float V1     = active ? Vn : V;                                    \
        float A1     = active ? An : A;                                    \
        bool  spike  = active && (V1 >= VTH_F);                            \
        V  = spike ? VRESET_F : V1;                                        \
        A  = spike ? (A1 + AINC_F) : A1;                                   \
        ls = spike ? t : ls;                                               \
        count += spike ? 1 : 0;                                            \
    } while (0)

__global__ __launch_bounds__(384, 1) void lif_sim_kernel(
    const float* __restrict__ ext,
    const float* __restrict__ inz,
    const float* __restrict__ vnz,
    float* __restrict__ rates)
{
    // [slot][array][t][neuron] : 6*3*8*128*4 = 72 KB
    __shared__ float slotmem[RING][3][C_STEPS][NPB];

    const int tid  = threadIdx.x;
    const int lane = tid & 63;
    const int w    = tid >> 6;          // 0..5
    const int n0   = blockIdx.x * NPB;

    if (w >= 2) {
        // ---------------- loader waves (4) ----------------
        const int lw = w - 2;           // 0..3
        // instruction idx = lw*12 + i: row r = idx>>1 (a = r>>3, tt = r&7),
        // half h = idx&1. Each instr: 64 consecutive floats (256B), one
        // timestep, half of the 128-neuron row. LDS dst wave-uniform.
        const float* pg[IPW];
        int loff[IPW];                  // float offset within a slot
#pragma unroll
        for (int i = 0; i < IPW; ++i) {
            const int idx = lw * IPW + i;     // 0..47
            const int r   = idx >> 1;         // 0..23
            const int h   = idx & 1;
            const int a   = r >> 3;           // 0..2
            const int tt  = r & 7;            // 0..7
            const float* ba = (a == 0) ? ext : ((a == 1) ? inz : vnz);
            pg[i]   = ba + (size_t)tt * BN + (n0 + h * 64 + lane);
            loff[i] = (a * C_STEPS + tt) * NPB + h * 64;
        }

        float* const slot0 = &slotmem[0][0][0][0];
        constexpr int SLOT_F = 3 * C_STEPS * NPB;   // 3072 floats per slot

        auto issue = [&](int j) {
            float* sb = slot0 + (j % RING) * SLOT_F;
#pragma unroll
            for (int i = 0; i < IPW; ++i) {
                __builtin_amdgcn_global_load_lds(
                    (const __attribute__((address_space(1))) void*)
                        (pg[i] + (size_t)j * BUF_STRIDE),
                    (__attribute__((address_space(3))) void*)(sb + loff[i]),
                    4, 0, 0);
            }
        };

        // prologue: buffers 0..3 in flight (48 instrs/wave outstanding)
        for (int j = 0; j < AHEAD; ++j) issue(j);

        for (int k = 0; k < NBUF; ++k) {
            // wave-private wait for buffer k: allowed outstanding =
            // 12 * min(AHEAD-1, NBUF-1-k)
            const int rem = NBUF - 1 - k;
            const int nb  = (rem < AHEAD - 1) ? rem : (AHEAD - 1);
            switch (nb) {
                case 3:  asm volatile("s_waitcnt vmcnt(36)" ::: "memory"); break;
                case 2:  asm volatile("s_waitcnt vmcnt(24)" ::: "memory"); break;
                case 1:  asm volatile("s_waitcnt vmcnt(12)" ::: "memory"); break;
                default: asm volatile("s_waitcnt vmcnt(0)"  ::: "memory"); break;
            }
            __builtin_amdgcn_sched_barrier(0);
            // barrier k: buffer k fully landed (each wave vouches for its rows)
            __builtin_amdgcn_s_barrier();
            __builtin_amdgcn_sched_barrier(0);
            // refill: slot (k+4)%6 == slot (k-2)%6; its readers finished
            // before barrier k-1 < barrier k -> safe.
            if (k + AHEAD < NBUF) issue(k + AHEAD);
        }
    } else {
        // ---------------- compute waves (2): 1 neuron per thread ----------------
        float V = 0.0f, A = 0.0f, ls = -1e9f;
        int count = 0;

        for (int k = 0; k < NBUF; ++k) {
            __builtin_amdgcn_s_barrier();
            __builtin_amdgcn_sched_barrier(0);
            const int s = k % RING;
#pragma unroll
            for (int c = 0; c < C_STEPS; ++c) {
                float ec = slotmem[s][0][c][tid];
                float ic = slotmem[s][1][c][tid];
                float vc = slotmem[s][2][c][tid];
                LIF_STEP(ec, ic, vc, k * C_STEPS + c);
            }
            __builtin_amdgcn_sched_barrier(0);   // keep reads inside the window
        }
        rates[n0 + tid] = (float)count * (1.0f / 1024.0f);
    }
}

// ---------------- readout: rates[16,2048] @ (Gn*0.1)[2048,512] ----------------
constexpr int KC   = 8;
constexpr int KCH  = NNEUR / KC;    // 256 k per chunk
constexpr int KSUB = 4;             // waves per block splitting the chunk
constexpr int KPT  = KCH / KSUB;    // 64 k per thread

__global__ __launch_bounds__(256) void readout_partial_kernel(
    const float* __restrict__ rates,
    const float* __restrict__ G,
    const float* __restrict__ cn,
    float* __restrict__ part)
{
    __shared__ float red[KSUB][64][BATCH + 1];

    const int tid = threadIdx.x;
    const int ml  = tid & 63;
    const int s   = tid >> 6;
    const int m   = blockIdx.x * 64 + ml;
    const int kc  = blockIdx.y;
    const int k0  = kc * KCH + s * KPT;

    float acc[BATCH];
#pragma unroll
    for (int b = 0; b < BATCH; ++b) acc[b] = 0.0f;

#pragma unroll 4
    for (int k = k0; k < k0 + KPT; ++k) {
        float g = G[(size_t)k * MCOLS + m];
        float c = cn[(size_t)k * MCOLS + m];
        float w = fmaxf(1e-8f, g * (1.0f + 0.1118f * c)) * 0.1f;  // Gn * READ_V
#pragma unroll
        for (int b = 0; b < BATCH; ++b) {
            acc[b] = fmaf(rates[b * NNEUR + k], w, acc[b]);
        }
    }

#pragma unroll
    for (int b = 0; b < BATCH; ++b) red[s][ml][b] = acc[b];
    __syncthreads();

    if (s == 0) {
#pragma unroll
        for (int b = 0; b < BATCH; ++b) {
            float v = ((red[0][ml][b] + red[1][ml][b]) + red[2][ml][b]) + red[3][ml][b];
            part[((size_t)kc * BATCH + b) * MCOLS + m] = v;
        }
    }
}

__global__ __launch_bounds__(256) void readout_reduce_kernel(
    const float* __restrict__ part,
    float* __restrict__ out)
{
    const int i = blockIdx.x * 256 + threadIdx.x;  // 0..8191 = b*512+m
    float s = 0.0f;
#pragma unroll
    for (int kc = 0; kc < KC; ++kc) {
        s += part[kc * (BATCH * MCOLS) + i];
    }
    out[i] = s;
}

extern "C" void kernel_launch(void* const* d_in, const int* in_sizes, int n_in,
                              void* d_out, int out_size, void* d_ws, size_t ws_size,
                              hipStream_t stream)
{
    const float* ext = (const float*)d_in[0];   // [T,B,N]
    const float* inz = (const float*)d_in[1];   // [T,B,N]
    const float* vnz = (const float*)d_in[2];   // [T,B,N]
    const float* G   = (const float*)d_in[3];   // [N,M]
    const float* cn  = (const float*)d_in[4];   // [N,M]
    float* out = (float*)d_out;                 // [B,M] = 8192

    float* rates = (float*)d_ws;                // 32768 floats
    float* part  = rates + BN;                  // 8*16*512 = 65536 floats

    lif_sim_kernel<<<BN / NPB, 384, 0, stream>>>(ext, inz, vnz, rates);
    readout_partial_kernel<<<dim3(MCOLS / 64, KC), 256, 0, stream>>>(rates, G, cn, part);
    readout_reduce_kernel<<<(BATCH * MCOLS) / 256, 256, 0, stream>>>(part, out);
}